// Round 1
// baseline (899.695 us; speedup 1.0000x reference)
//
#include <hip/hip_runtime.h>
#include <hip/hip_bf16.h>
#include <math.h>

#define EMBED 1024
#define FFN   4096
#define NW    8
#define MTOT  32768   // 16*2048

#define BM 128
#define BN 128
#define BK 64

typedef __attribute__((ext_vector_type(8))) short          short8v;   // 8 bf16 = 4 VGPR (MFMA frag)
typedef __attribute__((ext_vector_type(8))) unsigned short ushort8v;  // 16B store
typedef __attribute__((ext_vector_type(4))) float          f32x4;

typedef __attribute__((address_space(1))) void gvoid_t;
typedef __attribute__((address_space(3))) void svoid_t;

static __device__ __forceinline__ unsigned short bf16bits(float f) {
    __hip_bfloat16 h = __float2bfloat16(f);
    return *reinterpret_cast<unsigned short*>(&h);
}

// ---------------- W2 f32 -> bf16 (once, into ws) ----------------
__global__ __launch_bounds__(256) void cvtW2_kernel(const float* __restrict__ W2,
                                                    __hip_bfloat16* __restrict__ Bw) {
    const long i0 = ((long)blockIdx.x * 256 + threadIdx.x) * 8;
    const float4 a = *(const float4*)(W2 + i0);
    const float4 b = *(const float4*)(W2 + i0 + 4);
    float fs[8] = {a.x, a.y, a.z, a.w, b.x, b.y, b.z, b.w};
    ushort8v v;
#pragma unroll
    for (int t = 0; t < 8; ++t) v[t] = bf16bits(fs[t]);
    *reinterpret_cast<ushort8v*>(Bw + i0) = v;
}

// ---------------- producer: h[m,k] = relu(b1[k] + sum_w qz[m,w]*W1[k,w]) ----------------
// one wave per row; lane covers 8 k-chunks of 8 (vectorized 16B stores)
__global__ __launch_bounds__(256) void hprod_kernel(
    const float* __restrict__ x, const float* __restrict__ theta,
    const float* __restrict__ W1, const float* __restrict__ b1,
    __hip_bfloat16* __restrict__ h, int m0)
{
    const int wave = threadIdx.x >> 6, lane = threadIdx.x & 63;
    const int mrel = blockIdx.x * 4 + wave;        // row within chunk
    const long m   = (long)m0 + mrel;              // global row
    const float* xr = x + m * (long)EMBED;
    float qz[NW];
#pragma unroll
    for (int w = 0; w < NW; ++w)
        qz[w] = cosf(xr[w]) * cosf(theta[w]);      // <Z_w> = cos(x_w)cos(theta_w)
    __hip_bfloat16* hr = h + (long)mrel * FFN;
#pragma unroll
    for (int j = 0; j < 8; ++j) {
        const int k0 = j * 512 + lane * 8;
        ushort8v hv;
#pragma unroll
        for (int t = 0; t < 8; ++t) {
            const int k = k0 + t;
            const float4 wa = *(const float4*)(W1 + (long)k * NW);
            const float4 wb = *(const float4*)(W1 + (long)k * NW + 4);
            float acc = b1[k];
            acc = fmaf(qz[0], wa.x, acc); acc = fmaf(qz[1], wa.y, acc);
            acc = fmaf(qz[2], wa.z, acc); acc = fmaf(qz[3], wa.w, acc);
            acc = fmaf(qz[4], wb.x, acc); acc = fmaf(qz[5], wb.y, acc);
            acc = fmaf(qz[6], wb.z, acc); acc = fmaf(qz[7], wb.w, acc);
            hv[t] = bf16bits(fmaxf(acc, 0.0f));
        }
        *reinterpret_cast<ushort8v*>(hr + k0) = hv;
    }
}

// ---------------- GEMM: out[M,1024] = h[M,4096] @ W2[1024,4096]^T + b2 ----------------
// m97 structure: 128x128 tile, BK=64, 4 waves (2x2), 16x16x32 bf16 MFMA,
// global_load_lds width-16 staging, 2-barrier K-loop.
template<bool BW_BF16>
__global__ __launch_bounds__(256) void gemm_kernel(
    const __hip_bfloat16* __restrict__ A,   // [Mc][FFN] chunk-local h (bf16)
    const __hip_bfloat16* __restrict__ Bbf, // [EMBED][FFN] W2 bf16 (if BW_BF16)
    const float* __restrict__ Bf32,         // [EMBED][FFN] W2 f32 (fallback)
    const float* __restrict__ b2,
    float* __restrict__ out, int m0, int nPm)
{
    __shared__ __hip_bfloat16 As[BM * BK];
    __shared__ __hip_bfloat16 Bs[BN * BK];
    const int tid = threadIdx.x, wid = tid >> 6, lane = tid & 63;

    // XCD-affine mapping: blocks with bid%8==c land on XCD c; each XCD walks
    // all 8 pn panels of one pm before advancing -> A panel (1MB) L2-resident.
    const int bid = blockIdx.x;
    int pm, pn;
    if ((nPm & 7) == 0) { pm = (bid >> 6) * 8 + (bid & 7); pn = (bid >> 3) & 7; }
    else                { pm = bid >> 3;                    pn = bid & 7; }

    // staging geometry (global_load_lds: wave-uniform LDS base + lane*16B)
    const int ar = lane >> 3;            // row within 8-row chunk
    const int ac = (lane & 7) * 8;       // elem col within BK
    // B f32 fallback staging: thread -> row rb, half hoff (32 elems)
    const int rb = tid >> 1, hoff = (tid & 1) * 32;

    const int wr = wid >> 1, wc = wid & 1;
    const int l15 = lane & 15, l4 = lane >> 4;

    f32x4 acc[4][4];
#pragma unroll
    for (int i = 0; i < 4; ++i)
#pragma unroll
        for (int j = 0; j < 4; ++j) acc[i][j] = (f32x4){0.f, 0.f, 0.f, 0.f};

    for (int kt = 0; kt < FFN; kt += BK) {
        __syncthreads();
        // ---- stage A (h) via global_load_lds, 4 chunks/wave ----
#pragma unroll
        for (int i = 0; i < 4; ++i) {
            const int q = wid * 4 + i;                       // 16 chunks of 8 rows
            const __hip_bfloat16* gp =
                A + (long)(pm * BM + q * 8 + ar) * FFN + kt + ac;
            __builtin_amdgcn_global_load_lds((gvoid_t*)gp, (svoid_t*)(As + q * 8 * BK),
                                             16, 0, 0);
        }
        // ---- stage B (W2) ----
        if (BW_BF16) {
#pragma unroll
            for (int i = 0; i < 4; ++i) {
                const int q = wid * 4 + i;
                const __hip_bfloat16* gp =
                    Bbf + (long)(pn * BN + q * 8 + ar) * FFN + kt + ac;
                __builtin_amdgcn_global_load_lds((gvoid_t*)gp, (svoid_t*)(Bs + q * 8 * BK),
                                                 16, 0, 0);
            }
        } else {
            const float* w2row = Bf32 + (long)(pn * BN + rb) * FFN + hoff + kt;
            float4 f[8];
#pragma unroll
            for (int i = 0; i < 8; ++i) f[i] = *(const float4*)(w2row + i * 4);
#pragma unroll
            for (int i = 0; i < 4; ++i) {
                ushort8v v;
#pragma unroll
                for (int t = 0; t < 8; ++t)
                    v[t] = bf16bits(((const float*)&f[i * 2])[t]);
                *reinterpret_cast<ushort8v*>(&Bs[rb * BK + hoff + i * 8]) = v;
            }
        }
        __syncthreads();
        // ---- compute: 2 K-slices of 32, 16 MFMA each ----
#pragma unroll
        for (int kk = 0; kk < 2; ++kk) {
            short8v af[4], bfr[4];
#pragma unroll
            for (int mi = 0; mi < 4; ++mi)
                af[mi] = *reinterpret_cast<const short8v*>(
                    &As[(wr * 64 + mi * 16 + l15) * BK + kk * 32 + l4 * 8]);
#pragma unroll
            for (int ni = 0; ni < 4; ++ni)
                bfr[ni] = *reinterpret_cast<const short8v*>(
                    &Bs[(wc * 64 + ni * 16 + l15) * BK + kk * 32 + l4 * 8]);
#pragma unroll
            for (int mi = 0; mi < 4; ++mi)
#pragma unroll
                for (int ni = 0; ni < 4; ++ni)
                    acc[mi][ni] = __builtin_amdgcn_mfma_f32_16x16x32_bf16(
                        af[mi], bfr[ni], acc[mi][ni], 0, 0, 0);
        }
    }

    // ---- epilogue: + b2, f32 store. C/D: col=lane&15, row=(lane>>4)*4+reg ----
    const int gn0 = pn * BN + wc * 64;
    float bias[4];
#pragma unroll
    for (int ni = 0; ni < 4; ++ni) bias[ni] = b2[gn0 + ni * 16 + l15];
    const long gm0 = (long)m0 + pm * BM + wr * 64;
#pragma unroll
    for (int mi = 0; mi < 4; ++mi)
#pragma unroll
        for (int ni = 0; ni < 4; ++ni)
#pragma unroll
            for (int j = 0; j < 4; ++j) {
                const long row = gm0 + mi * 16 + l4 * 4 + j;
                out[row * EMBED + gn0 + ni * 16 + l15] = acc[mi][ni][j] + bias[ni];
            }
}

extern "C" void kernel_launch(void* const* d_in, const int* in_sizes, int n_in,
                              void* d_out, int out_size, void* d_ws, size_t ws_size,
                              hipStream_t stream)
{
    const float* x     = (const float*)d_in[0];
    const float* theta = (const float*)d_in[1];
    const float* W1    = (const float*)d_in[2];
    const float* b1    = (const float*)d_in[3];
    const float* W2    = (const float*)d_in[4];
    const float* b2    = (const float*)d_in[5];
    float* out = (float*)d_out;

    const size_t w2b = (size_t)EMBED * FFN * 2;                 // 8.4 MB bf16 W2
    const bool cvt = ws_size >= w2b + (size_t)128 * FFN * 2;    // room for W2 + >=1 chunk
    __hip_bfloat16* Bw = (__hip_bfloat16*)d_ws;
    __hip_bfloat16* h  = cvt ? (__hip_bfloat16*)((char*)d_ws + w2b)
                             : (__hip_bfloat16*)d_ws;
    const size_t avail = cvt ? ws_size - w2b : ws_size;

    long chunk = (long)((avail / ((size_t)FFN * 2)) & ~127UL);  // rows of h per pass
    if (chunk > MTOT) chunk = MTOT;
    if (chunk < 128)  chunk = 128;   // requires ws_size >= ~1MB

    if (cvt)
        cvtW2_kernel<<<(EMBED * FFN) / 2048, 256, 0, stream>>>(W2, Bw);

    for (long m0 = 0; m0 < MTOT; m0 += chunk) {
        const long rows = (MTOT - m0 < chunk) ? (MTOT - m0) : chunk;
        hprod_kernel<<<(int)(rows / 4), 256, 0, stream>>>(x, theta, W1, b1, h, (int)m0);
        const int nPm = (int)(rows / BM);
        if (cvt)
            gemm_kernel<true ><<<nPm * 8, 256, 0, stream>>>(h, Bw, W2, b2, out, (int)m0, nPm);
        else
            gemm_kernel<false><<<nPm * 8, 256, 0, stream>>>(h, Bw, W2, b2, out, (int)m0, nPm);
    }
}

// Round 2
// 487.044 us; speedup vs baseline: 1.8473x; 1.8473x over previous
//
#include <hip/hip_runtime.h>
#include <hip/hip_bf16.h>
#include <math.h>

#define EMBED 1024
#define FFN   4096
#define NW    8
#define MTOT  32768   // 16*2048

#define BM 128
#define BN 128
#define BK 64

#define STRIP 128     // rows per hprod block
#define KPT   8       // k-columns owned per hprod thread (256 thr -> 2048 k per block)

typedef __attribute__((ext_vector_type(8))) short          short8v;   // 8 bf16 = 4 VGPR (MFMA frag)
typedef __attribute__((ext_vector_type(8))) unsigned short ushort8v;  // 16B store
typedef __attribute__((ext_vector_type(4))) float          f32x4;

typedef __attribute__((address_space(1))) void gvoid_t;
typedef __attribute__((address_space(3))) void svoid_t;

static __device__ __forceinline__ unsigned short bf16bits(float f) {
    __hip_bfloat16 h = __float2bfloat16(f);
    return *reinterpret_cast<unsigned short*>(&h);
}

// ---------------- W2 f32 -> bf16 (once, into ws) ----------------
__global__ __launch_bounds__(256) void cvtW2_kernel(const float* __restrict__ W2,
                                                    __hip_bfloat16* __restrict__ Bw) {
    const long i0 = ((long)blockIdx.x * 256 + threadIdx.x) * 8;
    const float4 a = *(const float4*)(W2 + i0);
    const float4 b = *(const float4*)(W2 + i0 + 4);
    float fs[8] = {a.x, a.y, a.z, a.w, b.x, b.y, b.z, b.w};
    ushort8v v;
#pragma unroll
    for (int t = 0; t < 8; ++t) v[t] = bf16bits(fs[t]);
    *reinterpret_cast<ushort8v*>(Bw + i0) = v;
}

// ---------------- producer v2: h[m,k] = relu(b1[k] + sum_w qz[m,w]*W1[k,w]) ----------------
// Loop inversion vs v1: W1 slice lives in REGISTERS (loaded once per block),
// rows stream through. qz computed once per row into LDS, broadcast-read.
// Block covers 2048 k (tid*8), STRIP=128 rows. Stores: block writes 4KB
// contiguous per row. Write-BW-bound by design.
__global__ __launch_bounds__(256) void hprod2_kernel(
    const float* __restrict__ x, const float* __restrict__ theta,
    const float* __restrict__ W1, const float* __restrict__ b1,
    __hip_bfloat16* __restrict__ h, int m0)
{
    __shared__ float qz_lds[STRIP][NW];
    const int tid   = threadIdx.x;
    const int khalf = blockIdx.x & 1;
    const int strip = blockIdx.x >> 1;
    const int k0    = khalf * 2048 + tid * KPT;

    // W1 slice + b1 into registers (128KB W1 is L2-resident after first touch)
    float w1r[KPT][NW];
    float b1r[KPT];
#pragma unroll
    for (int i = 0; i < KPT; ++i) {
        const float4 a = *(const float4*)(W1 + (long)(k0 + i) * NW);
        const float4 b = *(const float4*)(W1 + (long)(k0 + i) * NW + 4);
        w1r[i][0] = a.x; w1r[i][1] = a.y; w1r[i][2] = a.z; w1r[i][3] = a.w;
        w1r[i][4] = b.x; w1r[i][5] = b.y; w1r[i][6] = b.z; w1r[i][7] = b.w;
        b1r[i] = b1[k0 + i];
    }

    // qz for this strip: thread t handles row t (16 cosf), tiny phase
    if (tid < STRIP) {
        const long m = (long)m0 + (long)strip * STRIP + tid;
        const float* xr = x + m * (long)EMBED;
#pragma unroll
        for (int w = 0; w < NW; ++w)
            qz_lds[tid][w] = cosf(xr[w]) * cosf(theta[w]);
    }
    __syncthreads();

    __hip_bfloat16* hp = h + ((long)strip * STRIP) * FFN + k0;
    for (int r = 0; r < STRIP; ++r) {
        float q[NW];
#pragma unroll
        for (int w = 0; w < NW; ++w) q[w] = qz_lds[r][w];   // same-addr broadcast
        ushort8v hv;
#pragma unroll
        for (int i = 0; i < KPT; ++i) {
            float acc = b1r[i];
#pragma unroll
            for (int w = 0; w < NW; ++w) acc = fmaf(q[w], w1r[i][w], acc);
            hv[i] = bf16bits(fmaxf(acc, 0.0f));
        }
        *reinterpret_cast<ushort8v*>(hp + (long)r * FFN) = hv;
    }
}

// ---------------- GEMM: out[M,1024] = h[M,4096] @ W2[1024,4096]^T + b2 ----------------
// m97 structure: 128x128 tile, BK=64, 4 waves (2x2), 16x16x32 bf16 MFMA,
// global_load_lds width-16 staging, 2-barrier K-loop. (unchanged from R1)
template<bool BW_BF16>
__global__ __launch_bounds__(256) void gemm_kernel(
    const __hip_bfloat16* __restrict__ A,   // [Mc][FFN] chunk-local h (bf16)
    const __hip_bfloat16* __restrict__ Bbf, // [EMBED][FFN] W2 bf16 (if BW_BF16)
    const float* __restrict__ Bf32,         // [EMBED][FFN] W2 f32 (fallback)
    const float* __restrict__ b2,
    float* __restrict__ out, int m0, int nPm)
{
    __shared__ __hip_bfloat16 As[BM * BK];
    __shared__ __hip_bfloat16 Bs[BN * BK];
    const int tid = threadIdx.x, wid = tid >> 6, lane = tid & 63;

    // XCD-affine mapping: blocks with bid%8==c land on XCD c; each XCD walks
    // all 8 pn panels of one pm before advancing -> A panel (1MB) L2-resident.
    const int bid = blockIdx.x;
    int pm, pn;
    if ((nPm & 7) == 0) { pm = (bid >> 6) * 8 + (bid & 7); pn = (bid >> 3) & 7; }
    else                { pm = bid >> 3;                    pn = bid & 7; }

    // staging geometry (global_load_lds: wave-uniform LDS base + lane*16B)
    const int ar = lane >> 3;            // row within 8-row chunk
    const int ac = (lane & 7) * 8;       // elem col within BK
    // B f32 fallback staging: thread -> row rb, half hoff (32 elems)
    const int rb = tid >> 1, hoff = (tid & 1) * 32;

    const int wr = wid >> 1, wc = wid & 1;
    const int l15 = lane & 15, l4 = lane >> 4;

    f32x4 acc[4][4];
#pragma unroll
    for (int i = 0; i < 4; ++i)
#pragma unroll
        for (int j = 0; j < 4; ++j) acc[i][j] = (f32x4){0.f, 0.f, 0.f, 0.f};

    for (int kt = 0; kt < FFN; kt += BK) {
        __syncthreads();
        // ---- stage A (h) via global_load_lds, 4 chunks/wave ----
#pragma unroll
        for (int i = 0; i < 4; ++i) {
            const int q = wid * 4 + i;                       // 16 chunks of 8 rows
            const __hip_bfloat16* gp =
                A + (long)(pm * BM + q * 8 + ar) * FFN + kt + ac;
            __builtin_amdgcn_global_load_lds((gvoid_t*)gp, (svoid_t*)(As + q * 8 * BK),
                                             16, 0, 0);
        }
        // ---- stage B (W2) ----
        if (BW_BF16) {
#pragma unroll
            for (int i = 0; i < 4; ++i) {
                const int q = wid * 4 + i;
                const __hip_bfloat16* gp =
                    Bbf + (long)(pn * BN + q * 8 + ar) * FFN + kt + ac;
                __builtin_amdgcn_global_load_lds((gvoid_t*)gp, (svoid_t*)(Bs + q * 8 * BK),
                                                 16, 0, 0);
            }
        } else {
            const float* w2row = Bf32 + (long)(pn * BN + rb) * FFN + hoff + kt;
            float4 f[8];
#pragma unroll
            for (int i = 0; i < 8; ++i) f[i] = *(const float4*)(w2row + i * 4);
#pragma unroll
            for (int i = 0; i < 4; ++i) {
                ushort8v v;
#pragma unroll
                for (int t = 0; t < 8; ++t)
                    v[t] = bf16bits(((const float*)&f[i * 2])[t]);
                *reinterpret_cast<ushort8v*>(&Bs[rb * BK + hoff + i * 8]) = v;
            }
        }
        __syncthreads();
        // ---- compute: 2 K-slices of 32, 16 MFMA each ----
#pragma unroll
        for (int kk = 0; kk < 2; ++kk) {
            short8v af[4], bfr[4];
#pragma unroll
            for (int mi = 0; mi < 4; ++mi)
                af[mi] = *reinterpret_cast<const short8v*>(
                    &As[(wr * 64 + mi * 16 + l15) * BK + kk * 32 + l4 * 8]);
#pragma unroll
            for (int ni = 0; ni < 4; ++ni)
                bfr[ni] = *reinterpret_cast<const short8v*>(
                    &Bs[(wc * 64 + ni * 16 + l15) * BK + kk * 32 + l4 * 8]);
#pragma unroll
            for (int mi = 0; mi < 4; ++mi)
#pragma unroll
                for (int ni = 0; ni < 4; ++ni)
                    acc[mi][ni] = __builtin_amdgcn_mfma_f32_16x16x32_bf16(
                        af[mi], bfr[ni], acc[mi][ni], 0, 0, 0);
        }
    }

    // ---- epilogue: + b2, f32 store. C/D: col=lane&15, row=(lane>>4)*4+reg ----
    const int gn0 = pn * BN + wc * 64;
    float bias[4];
#pragma unroll
    for (int ni = 0; ni < 4; ++ni) bias[ni] = b2[gn0 + ni * 16 + l15];
    const long gm0 = (long)m0 + pm * BM + wr * 64;
#pragma unroll
    for (int mi = 0; mi < 4; ++mi)
#pragma unroll
        for (int ni = 0; ni < 4; ++ni)
#pragma unroll
            for (int j = 0; j < 4; ++j) {
                const long row = gm0 + mi * 16 + l4 * 4 + j;
                out[row * EMBED + gn0 + ni * 16 + l15] = acc[mi][ni][j] + bias[ni];
            }
}

extern "C" void kernel_launch(void* const* d_in, const int* in_sizes, int n_in,
                              void* d_out, int out_size, void* d_ws, size_t ws_size,
                              hipStream_t stream)
{
    const float* x     = (const float*)d_in[0];
    const float* theta = (const float*)d_in[1];
    const float* W1    = (const float*)d_in[2];
    const float* b1    = (const float*)d_in[3];
    const float* W2    = (const float*)d_in[4];
    const float* b2    = (const float*)d_in[5];
    float* out = (float*)d_out;

    const size_t w2b = (size_t)EMBED * FFN * 2;                 // 8.4 MB bf16 W2
    const bool cvt = ws_size >= w2b + (size_t)128 * FFN * 2;    // room for W2 + >=1 chunk
    __hip_bfloat16* Bw = (__hip_bfloat16*)d_ws;
    __hip_bfloat16* h  = cvt ? (__hip_bfloat16*)((char*)d_ws + w2b)
                             : (__hip_bfloat16*)d_ws;
    const size_t avail = cvt ? ws_size - w2b : ws_size;

    long chunk = (long)((avail / ((size_t)FFN * 2)) & ~127UL);  // rows of h per pass
    if (chunk > MTOT) chunk = MTOT;
    if (chunk < 128)  chunk = 128;   // requires ws_size >= ~1MB

    if (cvt)
        cvtW2_kernel<<<(EMBED * FFN) / 2048, 256, 0, stream>>>(W2, Bw);

    for (long m0 = 0; m0 < MTOT; m0 += chunk) {
        const long rows = (MTOT - m0 < chunk) ? (MTOT - m0) : chunk;
        hprod2_kernel<<<(int)((rows / STRIP) * 2), 256, 0, stream>>>(x, theta, W1, b1, h, (int)m0);
        const int nPm = (int)(rows / BM);
        if (cvt)
            gemm_kernel<true ><<<nPm * 8, 256, 0, stream>>>(h, Bw, W2, b2, out, (int)m0, nPm);
        else
            gemm_kernel<false><<<nPm * 8, 256, 0, stream>>>(h, Bw, W2, b2, out, (int)m0, nPm);
    }
}

// Round 3
// 414.687 us; speedup vs baseline: 2.1696x; 1.1745x over previous
//
#include <hip/hip_runtime.h>
#include <hip/hip_bf16.h>
#include <math.h>

#define EMBED 1024
#define FFN   4096
#define NW    8
#define MTOT  32768   // 16*2048

#define BM 256
#define BN 128
#define BK 32
#define NT (FFN / BK)   // 128 K-tiles

#define STRIP 128
#define KPT   8

typedef __attribute__((ext_vector_type(8))) short          short8v;
typedef __attribute__((ext_vector_type(8))) unsigned short ushort8v;
typedef __attribute__((ext_vector_type(4))) float          f32x4;

typedef __attribute__((address_space(1))) void gvoid_t;
typedef __attribute__((address_space(3))) void svoid_t;

#define VMCNT(n)  asm volatile("s_waitcnt vmcnt(" #n ")" ::: "memory")
#define SCHEDB()  __builtin_amdgcn_sched_barrier(0)
#define BAR()     __builtin_amdgcn_s_barrier()

static __device__ __forceinline__ unsigned short bf16bits(float f) {
    __hip_bfloat16 h = __float2bfloat16(f);
    return *reinterpret_cast<unsigned short*>(&h);
}

// ---------------- W2 f32 -> bf16 (once, into ws) ----------------
__global__ __launch_bounds__(256) void cvtW2_kernel(const float* __restrict__ W2,
                                                    __hip_bfloat16* __restrict__ Bw) {
    const long i0 = ((long)blockIdx.x * 256 + threadIdx.x) * 8;
    const float4 a = *(const float4*)(W2 + i0);
    const float4 b = *(const float4*)(W2 + i0 + 4);
    float fs[8] = {a.x, a.y, a.z, a.w, b.x, b.y, b.z, b.w};
    ushort8v v;
#pragma unroll
    for (int t = 0; t < 8; ++t) v[t] = bf16bits(fs[t]);
    *reinterpret_cast<ushort8v*>(Bw + i0) = v;
}

// ---------------- producer: h[m,k] = relu(b1[k] + qz[m,:]·W1[k,:]) ----------------
// W1 slice in registers, rows stream, qz broadcast from LDS (R2 version, ~5us)
__global__ __launch_bounds__(256) void hprod2_kernel(
    const float* __restrict__ x, const float* __restrict__ theta,
    const float* __restrict__ W1, const float* __restrict__ b1,
    __hip_bfloat16* __restrict__ h, int m0)
{
    __shared__ float qz_lds[STRIP][NW];
    const int tid   = threadIdx.x;
    const int khalf = blockIdx.x & 1;
    const int strip = blockIdx.x >> 1;
    const int k0    = khalf * 2048 + tid * KPT;

    float w1r[KPT][NW];
    float b1r[KPT];
#pragma unroll
    for (int i = 0; i < KPT; ++i) {
        const float4 a = *(const float4*)(W1 + (long)(k0 + i) * NW);
        const float4 b = *(const float4*)(W1 + (long)(k0 + i) * NW + 4);
        w1r[i][0] = a.x; w1r[i][1] = a.y; w1r[i][2] = a.z; w1r[i][3] = a.w;
        w1r[i][4] = b.x; w1r[i][5] = b.y; w1r[i][6] = b.z; w1r[i][7] = b.w;
        b1r[i] = b1[k0 + i];
    }

    if (tid < STRIP) {
        const long m = (long)m0 + (long)strip * STRIP + tid;
        const float* xr = x + m * (long)EMBED;
#pragma unroll
        for (int w = 0; w < NW; ++w)
            qz_lds[tid][w] = cosf(xr[w]) * cosf(theta[w]);
    }
    __syncthreads();

    __hip_bfloat16* hp = h + ((long)strip * STRIP) * FFN + k0;
    for (int r = 0; r < STRIP; ++r) {
        float q[NW];
#pragma unroll
        for (int w = 0; w < NW; ++w) q[w] = qz_lds[r][w];
        ushort8v hv;
#pragma unroll
        for (int i = 0; i < KPT; ++i) {
            float acc = b1r[i];
#pragma unroll
            for (int w = 0; w < NW; ++w) acc = fmaf(q[w], w1r[i][w], acc);
            hv[i] = bf16bits(fmaxf(acc, 0.0f));
        }
        *reinterpret_cast<ushort8v*>(hp + (long)r * FFN) = hv;
    }
}

// ---------------- GEMM v3: deep-pipelined counted-vmcnt ----------------
// out[M,1024] = h[M,4096] @ W2bf[1024,4096]^T + b2
// BM=256 BN=128 BK=32; 4 waves (2x2), wave owns 128x64 (8x4 frags, 32 MFMA/tile).
// LDS: A 3-deep (48KB) + B 2-deep (16KB) = 64KB -> 2 blocks/CU.
// Pipeline (per-wave FIFO): iter t issues [B(t+1), A(t+2)], then vmcnt(10)+barrier
//   => everything older than the newest 10 loads (= A(t+1),B(t+1),A(t+2)) landed
//   => tile t fully in LDS, collectively (barrier). A gets ~2-iter HBM-latency
//   cover; B (L2-resident W2) 1-iter. Never vmcnt(0) in main loop (T4).
// BK=32 rows = 64B: frag reads are bank-uniform (8 lanes/16B-slot) -> no swizzle.
__global__ __launch_bounds__(256, 2) void gemm3_kernel(
    const __hip_bfloat16* __restrict__ A,   // [rows][FFN] chunk-local h
    const __hip_bfloat16* __restrict__ Bw,  // [EMBED][FFN] W2 bf16
    const float* __restrict__ b2,
    float* __restrict__ out, long m0, int nPm)
{
    __shared__ __align__(16) __hip_bfloat16 As[3][BM][BK];  // 48 KB
    __shared__ __align__(16) __hip_bfloat16 Bs[2][BN][BK];  // 16 KB

    const int tid = threadIdx.x, wid = tid >> 6, lane = tid & 63;
    const int l15 = lane & 15, l4 = lane >> 4;
    const int wr = wid >> 1, wc = wid & 1;

    // XCD-affine: xcd = bid&7 owns pm range [xcd*pmx, +pmx), pn slow-varying
    int pm, pn;
    { const int xcd = blockIdx.x & 7, k = blockIdx.x >> 3, pmx = nPm >> 3;
      pn = k / pmx; pm = xcd * pmx + (k - pn * pmx); }

    const int srow = lane >> 2;          // gload: 4 lanes/row, 16 rows/call
    const int scol = (lane & 3) * 8;     // 16B per lane

    const __hip_bfloat16* Abase = A  + (long)(pm * BM + wid * 64) * FFN;
    const __hip_bfloat16* Bbase = Bw + (long)(pn * BN + wid * 32) * FFN;

    f32x4 acc[8][4];
#pragma unroll
    for (int i = 0; i < 8; ++i)
#pragma unroll
        for (int j = 0; j < 4; ++j) acc[i][j] = (f32x4){0.f, 0.f, 0.f, 0.f};

#define STAGE_A(t) do {                                                          \
    const int _b = (t) % 3;                                                      \
    const __hip_bfloat16* _g = Abase + (long)srow * FFN + (t) * BK + scol;       \
    __hip_bfloat16* _s = &As[_b][wid * 64][0];                                   \
    _Pragma("unroll")                                                            \
    for (int _gi = 0; _gi < 4; ++_gi)                                            \
        __builtin_amdgcn_global_load_lds((gvoid_t*)(_g + (long)(_gi*16)*FFN),    \
                                         (svoid_t*)(_s + _gi*16*BK), 16, 0, 0);  \
} while (0)

#define STAGE_B(t) do {                                                          \
    const int _b = (t) & 1;                                                      \
    const __hip_bfloat16* _g = Bbase + (long)srow * FFN + (t) * BK + scol;       \
    __hip_bfloat16* _s = &Bs[_b][wid * 32][0];                                   \
    _Pragma("unroll")                                                            \
    for (int _gi = 0; _gi < 2; ++_gi)                                            \
        __builtin_amdgcn_global_load_lds((gvoid_t*)(_g + (long)(_gi*16)*FFN),    \
                                         (svoid_t*)(_s + _gi*16*BK), 16, 0, 0);  \
} while (0)

    // prologue (FIFO order must match steady state: ..., B(t), A(t+1), ...)
    STAGE_A(0); STAGE_B(0); STAGE_A(1);

    for (int t = 0; t < NT; ++t) {
        if (t + 1 < NT) STAGE_B(t + 1);
        if (t + 2 < NT) STAGE_A(t + 2);
        if (t < NT - 2)       VMCNT(10);   // newest 10 = A(t+1),B(t+1),A(t+2)
        else if (t == NT - 2) VMCNT(6);    // newest 6 = A(NT-1),B(NT-1)
        else                  VMCNT(0);    // last tile
        SCHEDB(); BAR(); SCHEDB();         // tile t collectively ready

        const int ba = t % 3, bb = t & 1;
        short8v bv[4], av[8];
#pragma unroll
        for (int ni = 0; ni < 4; ++ni)
            bv[ni] = *reinterpret_cast<const short8v*>(
                &Bs[bb][wc * 64 + ni * 16 + l15][l4 * 8]);
#pragma unroll
        for (int mi = 0; mi < 8; ++mi)
            av[mi] = *reinterpret_cast<const short8v*>(
                &As[ba][wr * 128 + mi * 16 + l15][l4 * 8]);

        __builtin_amdgcn_s_setprio(1);
#pragma unroll
        for (int mi = 0; mi < 8; ++mi)
#pragma unroll
            for (int ni = 0; ni < 4; ++ni)
                acc[mi][ni] = __builtin_amdgcn_mfma_f32_16x16x32_bf16(
                    av[mi], bv[ni], acc[mi][ni], 0, 0, 0);
        __builtin_amdgcn_s_setprio(0);
        SCHEDB(); BAR();                   // retire tile t's slots
    }

#undef STAGE_A
#undef STAGE_B

    // epilogue: + b2, f32 store. C/D: col=lane&15, row=(lane>>4)*4+reg
    const int gn0 = pn * BN + wc * 64;
    float bias[4];
#pragma unroll
    for (int ni = 0; ni < 4; ++ni) bias[ni] = b2[gn0 + ni * 16 + l15];
    const long gm0 = m0 + (long)pm * BM + wr * 128;
#pragma unroll
    for (int mi = 0; mi < 8; ++mi)
#pragma unroll
        for (int ni = 0; ni < 4; ++ni)
#pragma unroll
            for (int j = 0; j < 4; ++j) {
                const long row = gm0 + mi * 16 + l4 * 4 + j;
                out[row * EMBED + gn0 + ni * 16 + l15] = acc[mi][ni][j] + bias[ni];
            }
}

extern "C" void kernel_launch(void* const* d_in, const int* in_sizes, int n_in,
                              void* d_out, int out_size, void* d_ws, size_t ws_size,
                              hipStream_t stream)
{
    const float* x     = (const float*)d_in[0];
    const float* theta = (const float*)d_in[1];
    const float* W1    = (const float*)d_in[2];
    const float* b1    = (const float*)d_in[3];
    const float* W2    = (const float*)d_in[4];
    const float* b2    = (const float*)d_in[5];
    float* out = (float*)d_out;

    const size_t w2b = (size_t)EMBED * FFN * 2;          // 8.4 MB bf16 W2
    __hip_bfloat16* Bw = (__hip_bfloat16*)d_ws;
    __hip_bfloat16* h  = (__hip_bfloat16*)((char*)d_ws + w2b);
    const size_t avail = ws_size > w2b ? ws_size - w2b : 0;

    long chunk = (long)((avail / ((size_t)FFN * 2)) & ~2047UL); // mult of 2048 rows
    if (chunk > MTOT) chunk = MTOT;
    if (chunk < 2048) chunk = 2048;   // ws proven >= 277MB in R2; full-size path

    cvtW2_kernel<<<(EMBED * FFN) / 2048, 256, 0, stream>>>(W2, Bw);

    for (long m0 = 0; m0 < MTOT; m0 += chunk) {
        const long rows = (MTOT - m0 < chunk) ? (MTOT - m0) : chunk;
        hprod2_kernel<<<(int)((rows / STRIP) * 2), 256, 0, stream>>>(
            x, theta, W1, b1, h, (int)m0);
        const int nPm = (int)(rows / BM);
        gemm3_kernel<<<nPm * 8, 256, 0, stream>>>(h, Bw, b2, out, m0, nPm);
    }
}